// Round 3
// baseline (106.006 us; speedup 1.0000x reference)
//
#include <hip/hip_runtime.h>
#include <hip/hip_bf16.h>

// EmbeddingShard: out[t, :] = (W_full[tok[t], :] + sum_s b[s, :]) / SHARDS
// x: [16384] int32 tokens; W_full: [50400, 4096] f32; b: [8, 4096] f32;
// out: [16384, 4096] f32. Pure memory-bound gather (~537 MB HBM traffic).
//
// R2 lesson: __builtin_nontemporal_store on the output diverged under
// graph-replay + post-timing readback (absmax 2.5e-3). Plain stores only.

#define D_MODEL 4096
#define SHARDS 8

typedef float f32x4 __attribute__((ext_vector_type(4)));

// Step 1: bs[d] = sum_s b[s][d] (unscaled; main kernel does (w+bs)*0.125f,
// exact /8 in fp32, matching reference op order within fp32 noise).
__global__ void bias_sum_kernel(const float* __restrict__ b, float* __restrict__ bs) {
    int d = blockIdx.x * blockDim.x + threadIdx.x;
    if (d < D_MODEL) {
        float s = 0.0f;
#pragma unroll
        for (int i = 0; i < SHARDS; ++i) s += b[i * D_MODEL + d];
        bs[d] = s;
    }
}

// Step 2: one token row per block (grid = ntok = 16384 independent blocks so
// the scheduler hides the tok[t] -> row-gather dependent-load latency).
// 256 threads x 4 float4 each, fully coalesced 16B/lane. Plain stores.
__global__ __launch_bounds__(256) void gather_kernel(const int* __restrict__ tok,
                                                     const float* __restrict__ W,
                                                     const float* __restrict__ bs,
                                                     float* __restrict__ out) {
    const int t = blockIdx.x;
    const int tid = threadIdx.x;
    const int row = tok[t];  // block-uniform -> scalar load

    const f32x4* wrow = reinterpret_cast<const f32x4*>(W) + (size_t)row * (D_MODEL / 4);
    const f32x4* bs4  = reinterpret_cast<const f32x4*>(bs);
    f32x4*       orow = reinterpret_cast<f32x4*>(out) + (size_t)t * (D_MODEL / 4);

#pragma unroll
    for (int j = 0; j < 4; ++j) {
        f32x4 w  = wrow[tid + j * 256];
        f32x4 bv = bs4[tid + j * 256];   // L2-resident (16 KB)
        orow[tid + j * 256] = (w + bv) * 0.125f;
    }
}

extern "C" void kernel_launch(void* const* d_in, const int* in_sizes, int n_in,
                              void* d_out, int out_size, void* d_ws, size_t ws_size,
                              hipStream_t stream) {
    const int*   tok = (const int*)d_in[0];     // [16384]
    const float* W   = (const float*)d_in[1];   // [50400, 4096]
    const float* b   = (const float*)d_in[2];   // [8, 4096]
    float*       out = (float*)d_out;           // [16384, 4096]
    float*       bs  = (float*)d_ws;            // [4096] scratch

    const int ntok = in_sizes[0];               // 16384

    bias_sum_kernel<<<(D_MODEL + 255) / 256, 256, 0, stream>>>(b, bs);
    gather_kernel<<<ntok, 256, 0, stream>>>(tok, W, bs, out);
}